// Round 17
// baseline (182.945 us; speedup 1.0000x reference)
//
#include <hip/hip_runtime.h>
#include <hip/hip_bf16.h>
#include <cstdint>

// Problem: B=32, T1=T2=512, D=128, gamma=1.0
// out[b] = softDTW( 1 - cos_sim(x[b], y[b]) )
//
// ws layout (floats):
//   D : 32*512*512 = 8,388,608   (cost/ln2, ROW-MAJOR [b][i][j])
// R17: dropped the anti-diagonal "skew" layout. DP lanes have a FIXED row,
// so row-major = each lane streams sequentially through its own row
// (4 B/phase; 64B line serves 16 phases; 512 lines = 32 KB = L1).

#define BT      32
#define TLEN    512
#define DF      128
#define BIGV    1e30f
#define INV_LN2 1.44269504088896340f
#define LN2     0.69314718055994531f

// ------------------------------------------------- cosine-dist GEMM (row-major)
// 64x128 tile, grid (4,8,32) = 1024 blocks = 4 blocks/CU. Fused norms.
// R17: epilogue is plain coalesced float4 stores — no LDS transpose pass,
// no scatter, 2 fewer barriers.
#define KC    32
#define SPADX 68
#define SPADY 132

__global__ __launch_bounds__(256) void sdtw_gemm(const float* __restrict__ x,
                                                 const float* __restrict__ y,
                                                 float* __restrict__ D) {
    __shared__ float smem[6400];             // stage xs[32][68]+ys[32][132]
    __shared__ float rsx[64], rsy[128];      // row/col sumsq
    float* xs = smem;
    float* ys = smem + KC * SPADX;

    const int b  = blockIdx.z;
    const int r0 = blockIdx.y * 64;
    const int c0 = blockIdx.x * 128;
    const int tid = threadIdx.x;
    const int tx = tid & 15, ty = tid >> 4;

    const float* xb = x + ((size_t)b * TLEN + r0) * DF;
    const float* yb = y + ((size_t)b * TLEN + c0) * DF;

    float acc[4][8];
    #pragma unroll
    for (int i = 0; i < 4; ++i)
        #pragma unroll
        for (int j = 0; j < 8; ++j) acc[i][j] = 0.0f;

    float psx[2] = {0, 0}, psy[4] = {0, 0, 0, 0};

    float4 rx[2], ry[4];
    #pragma unroll
    for (int i = 0; i < 2; ++i) {
        int g = tid + i * 256, row = g >> 3, kq = g & 7;
        rx[i] = *reinterpret_cast<const float4*>(xb + (size_t)row * DF + kq * 4);
    }
    #pragma unroll
    for (int i = 0; i < 4; ++i) {
        int g = tid + i * 256, row = g >> 3, kq = g & 7;
        ry[i] = *reinterpret_cast<const float4*>(yb + (size_t)row * DF + kq * 4);
    }

    for (int kb = 0; kb < DF; kb += KC) {
        __syncthreads();
        #pragma unroll
        for (int i = 0; i < 2; ++i) {
            int g = tid + i * 256, row = g >> 3, kq = g & 7;
            xs[(kq * 4 + 0) * SPADX + row] = rx[i].x;
            xs[(kq * 4 + 1) * SPADX + row] = rx[i].y;
            xs[(kq * 4 + 2) * SPADX + row] = rx[i].z;
            xs[(kq * 4 + 3) * SPADX + row] = rx[i].w;
            psx[i] = fmaf(rx[i].x, rx[i].x, psx[i]);
            psx[i] = fmaf(rx[i].y, rx[i].y, psx[i]);
            psx[i] = fmaf(rx[i].z, rx[i].z, psx[i]);
            psx[i] = fmaf(rx[i].w, rx[i].w, psx[i]);
        }
        #pragma unroll
        for (int i = 0; i < 4; ++i) {
            int g = tid + i * 256, row = g >> 3, kq = g & 7;
            ys[(kq * 4 + 0) * SPADY + row] = ry[i].x;
            ys[(kq * 4 + 1) * SPADY + row] = ry[i].y;
            ys[(kq * 4 + 2) * SPADY + row] = ry[i].z;
            ys[(kq * 4 + 3) * SPADY + row] = ry[i].w;
            psy[i] = fmaf(ry[i].x, ry[i].x, psy[i]);
            psy[i] = fmaf(ry[i].y, ry[i].y, psy[i]);
            psy[i] = fmaf(ry[i].z, ry[i].z, psy[i]);
            psy[i] = fmaf(ry[i].w, ry[i].w, psy[i]);
        }
        __syncthreads();
        if (kb + KC < DF) {
            #pragma unroll
            for (int i = 0; i < 2; ++i) {
                int g = tid + i * 256, row = g >> 3, kq = g & 7;
                rx[i] = *reinterpret_cast<const float4*>(xb + (size_t)row * DF + (kb + KC) + kq * 4);
            }
            #pragma unroll
            for (int i = 0; i < 4; ++i) {
                int g = tid + i * 256, row = g >> 3, kq = g & 7;
                ry[i] = *reinterpret_cast<const float4*>(yb + (size_t)row * DF + (kb + KC) + kq * 4);
            }
        }
        #pragma unroll
        for (int k = 0; k < KC; ++k) {
            float ax[4], ay[8];
            *reinterpret_cast<float4*>(&ax[0]) = *reinterpret_cast<const float4*>(&xs[k * SPADX + ty * 4]);
            *reinterpret_cast<float4*>(&ay[0]) = *reinterpret_cast<const float4*>(&ys[k * SPADY + tx * 8]);
            *reinterpret_cast<float4*>(&ay[4]) = *reinterpret_cast<const float4*>(&ys[k * SPADY + tx * 8 + 4]);
            #pragma unroll
            for (int i = 0; i < 4; ++i)
                #pragma unroll
                for (int j = 0; j < 8; ++j)
                    acc[i][j] = fmaf(ax[i], ay[j], acc[i][j]);
        }
    }

    #pragma unroll
    for (int o = 1; o <= 4; o <<= 1) {
        psx[0] += __shfl_xor(psx[0], o);
        psx[1] += __shfl_xor(psx[1], o);
        psy[0] += __shfl_xor(psy[0], o);
        psy[1] += __shfl_xor(psy[1], o);
        psy[2] += __shfl_xor(psy[2], o);
        psy[3] += __shfl_xor(psy[3], o);
    }
    if ((tid & 7) == 0) {
        #pragma unroll
        for (int i = 0; i < 2; ++i) rsx[(tid + i * 256) >> 3] = psx[i];
        #pragma unroll
        for (int i = 0; i < 4; ++i) rsy[(tid + i * 256) >> 3] = psy[i];
    }

    __syncthreads();
    float rn[4], cn[8];
    #pragma unroll
    for (int i = 0; i < 4; ++i) rn[i] = 1.0f / fmaxf(sqrtf(rsx[ty * 4 + i]), 1e-12f);
    #pragma unroll
    for (int j = 0; j < 8; ++j) cn[j] = 1.0f / fmaxf(sqrtf(rsy[tx * 8 + j]), 1e-12f);

    // coalesced row-major store: D[b][r0+ty*4+i][c0+tx*8 ..+8]
    float* Db = D + ((size_t)b * TLEN + r0) * TLEN + c0;
    #pragma unroll
    for (int i = 0; i < 4; ++i) {
        float4 v0, v1;
        v0.x = (1.0f - acc[i][0] * rn[i] * cn[0]) * INV_LN2;
        v0.y = (1.0f - acc[i][1] * rn[i] * cn[1]) * INV_LN2;
        v0.z = (1.0f - acc[i][2] * rn[i] * cn[2]) * INV_LN2;
        v0.w = (1.0f - acc[i][3] * rn[i] * cn[3]) * INV_LN2;
        v1.x = (1.0f - acc[i][4] * rn[i] * cn[4]) * INV_LN2;
        v1.y = (1.0f - acc[i][5] * rn[i] * cn[5]) * INV_LN2;
        v1.z = (1.0f - acc[i][6] * rn[i] * cn[6]) * INV_LN2;
        v1.w = (1.0f - acc[i][7] * rn[i] * cn[7]) * INV_LN2;
        *reinterpret_cast<float4*>(Db + (size_t)(ty * 4 + i) * TLEN + tx * 8)     = v0;
        *reinterpret_cast<float4*>(Db + (size_t)(ty * 4 + i) * TLEN + tx * 8 + 4) = v1;
    }
}

// ----------------------------------------------------------------- DTW DP
// Structure = R9/R14 (best measured). 8 waves, lane owns row r = 64*chunk+lt,
// chunk remap c = ((ww&3)<<1)|(ww>>2); chunk c handles diag kd at phase
// kd+16c; one __syncthreads per 16-phase segment; JUNK/PARTIAL/INTERIOR
// modes; DPP lane-0 patch; hoisted boundary quads.
// R17: cost loads are per-lane sequential through the lane's OWN row of the
// row-major D (j = kd - r advances 1/phase). Per-lane med3 clamp on j makes
// one uniform load path (junk values masked as before).

__device__ __forceinline__ float dpp_shr1_old(float old, float x) {
    return __builtin_bit_cast(float,
        __builtin_amdgcn_update_dpp(__builtin_bit_cast(int, old),
                                    __builtin_bit_cast(int, x),
                                    0x138 /*wave_shr:1*/, 0xF, 0xF, false));
}

__device__ __forceinline__ int clampj(int v) {
    return v < 0 ? 0 : (v > TLEN - 1 ? TLEN - 1 : v);
}

#define PH(s, CC, PN, PO, NQC, MASKED)                                         \
  {                                                                            \
    float up_ = dpp_shr1_old(bd_up, PN);     /* lane0 <- bd_up */              \
    float dg_ = dgs;                         /* patched up_ of prev phase */   \
    float m_   = fminf(fminf(dg_, PN), up_);                                   \
    float mid_ = __builtin_amdgcn_fmed3f(dg_, PN, up_);                        \
    float mx_  = fmaxf(fmaxf(dg_, PN), up_);                                   \
    float e_   = 1.0f + __builtin_amdgcn_exp2f(m_ - mid_)                      \
                      + __builtin_amdgcn_exp2f(m_ - mx_);                      \
    float v_   = CC + m_ - __builtin_amdgcn_logf(e_);                          \
    PO = (MASKED) ? (((unsigned)(vb0 + (s)) < 512u) ? v_ : vBig) : v_;         \
    if (((s) & 3) == 0) bq.x = PO;                                             \
    if (((s) & 3) == 1) bq.y = PO;                                             \
    if (((s) & 3) == 2) bq.z = PO;                                             \
    if (((s) & 3) == 3) { bq.w = PO;                                           \
      if (lt == 63) bnd4[c + 1][(q0 + ((s) >> 2)) & 7] = bq; }                 \
    bd_up = (NQC);                                                             \
    dgs = up_;                                                                 \
    CC = skb[clampj(vb0 + (s) + 8)];                                           \
  }

#define SEG_BODY(MASKED)                                                       \
    PH(0,  c0, P, Q, nq0.x, MASKED) PH(1,  c1, Q, P, nq0.y, MASKED)            \
    PH(2,  c2, P, Q, nq0.z, MASKED) PH(3,  c3, Q, P, nq0.w, MASKED)            \
    PH(4,  c4, P, Q, nq1.x, MASKED) PH(5,  c5, Q, P, nq1.y, MASKED)            \
    PH(6,  c6, P, Q, nq1.z, MASKED) PH(7,  c7, Q, P, nq1.w, MASKED)            \
    PH(8,  c0, P, Q, nq2.x, MASKED) PH(9,  c1, Q, P, nq2.y, MASKED)            \
    PH(10, c2, P, Q, nq2.z, MASKED) PH(11, c3, Q, P, nq2.w, MASKED)            \
    PH(12, c4, P, Q, nq3.x, MASKED) PH(13, c5, Q, P, nq3.y, MASKED)            \
    PH(14, c6, P, Q, nq3.z, MASKED) PH(15, c7, Q, P, nq3.w, MASKED)

#define PRIME_J(VB)                                                            \
    c0 = skb[clampj((VB) + 0)];                                                \
    c1 = skb[clampj((VB) + 1)];                                                \
    c2 = skb[clampj((VB) + 2)];                                                \
    c3 = skb[clampj((VB) + 3)];                                                \
    c4 = skb[clampj((VB) + 4)];                                                \
    c5 = skb[clampj((VB) + 5)];                                                \
    c6 = skb[clampj((VB) + 6)];                                                \
    c7 = skb[clampj((VB) + 7)];

__global__ __launch_bounds__(512) void sdtw_dp(const float* __restrict__ D,
                                               float* __restrict__ out) {
    const int b   = blockIdx.x;
    const int tid = threadIdx.x;
    const int ww  = tid >> 6;                    // hardware wave id
    const int c   = ((ww & 3) << 1) | (ww >> 2); // chunk (SIMD-aware remap)
    const int lt  = tid & 63;
    const int row = 64 * c + lt;
    const float* skb = D + ((size_t)b * TLEN + row) * TLEN;   // lane's own row

    __shared__ float4 bnd4[9][8];                // [consumer chunk][quad slot]
    if (tid < 288) ((float*)bnd4)[tid] = BIGV;

    float P = BIGV, Q = BIGV;
    float vBig  = BIGV;
    float bd_up = BIGV;
    float dgs   = (tid == 0) ? 0.0f : BIGV;      // R(0,0)=0 at kd=0 (chunk0 lane0)
    float4 bq = make_float4(BIGV, BIGV, BIGV, BIGV);

    __syncthreads();

    float c0, c1, c2, c3, c4, c5, c6, c7;
    PRIME_J(-row)                                // real for chunk 0; re-primed at warm-up

    for (int s = 0; s < 71; ++s) {
        const int sw  = s - 5 * c;               // wave-uniform
        const int kd0 = 16 * (s - c);
        const int q0  = (kd0 >> 2) & 7;
        const int vb0 = kd0 - row;               // j at phase 0 of this segment

        if (sw >= -1 && sw <= 35) {
            float4 nq0 = bnd4[c][q0];
            float4 nq1 = bnd4[c][(q0 + 1) & 7];
            float4 nq2 = bnd4[c][(q0 + 2) & 7];
            float4 nq3 = bnd4[c][(q0 + 3) & 7];
            if (sw == -1) { PRIME_J(vb0) }       // warm-up: re-prime prefetch
            if (sw >= 4 && sw <= 31) { SEG_BODY(0) }   // interior (no mask)
            else                     { SEG_BODY(1) }   // staircase/warm-up
        } else {
            if (lt == 63) {                      // junk: keep boundary cadence
                float4 bigq = make_float4(BIGV, BIGV, BIGV, BIGV);
                bnd4[c + 1][q0]           = bigq;
                bnd4[c + 1][(q0 + 1) & 7] = bigq;
                bnd4[c + 1][(q0 + 2) & 7] = bigq;
                bnd4[c + 1][(q0 + 3) & 7] = bigq;
            }
        }
        __syncthreads();
    }

    if (tid == 511) out[b] = Q * LN2;            // chunk 7, row 511: R'(512,512)*ln2
}

// ---------------------------------------------------------------- launcher
extern "C" void kernel_launch(void* const* d_in, const int* in_sizes, int n_in,
                              void* d_out, int out_size, void* d_ws, size_t ws_size,
                              hipStream_t stream) {
    const float* x = (const float*)d_in[0];
    const float* y = (const float*)d_in[1];
    float* outp = (float*)d_out;

    float* D = (float*)d_ws;                     // 8,388,608 floats (33.5 MB)

    sdtw_gemm<<<dim3(4, 8, BT), dim3(256), 0, stream>>>(x, y, D);
    sdtw_dp<<<dim3(BT), dim3(512), 0, stream>>>(D, outp);
}

// Round 18
// 122.648 us; speedup vs baseline: 1.4916x; 1.4916x over previous
//
#include <hip/hip_runtime.h>
#include <hip/hip_bf16.h>
#include <cstdint>

// Problem: B=32, T1=T2=512, D=128, gamma=1.0
// out[b] = softDTW( 1 - cos_sim(x[b], y[b]) )
//
// ws layout:
//   skew : 32*1023*512 floats = 16,760,832   (cost/ln2, anti-diagonal layout)
//   xnb  : 32*512*128 bf16 (as 1,048,576 uints)
//   ynb  : same

#define BT      32
#define TLEN    512
#define DF      128
#define NDIAG   1023          // kd = 0..1022
#define BIGV    1e30f
#define INV_LN2 1.44269504088896340f
#define LN2     0.69314718055994531f

typedef short bf16x8 __attribute__((ext_vector_type(8)));
typedef float f32x4  __attribute__((ext_vector_type(4)));

__device__ __forceinline__ unsigned f2bf(float f) {     // RNE f32 -> bf16 bits
    unsigned u = __builtin_bit_cast(unsigned, f);
    return (u + 0x7FFFu + ((u >> 16) & 1u)) >> 16;
}

// ---------------------------------------------- normalize + cast to bf16
// gridDim.y: 0 -> x, 1 -> y. One wave per row.
__global__ __launch_bounds__(256) void sdtw_normcast(const float* __restrict__ x,
                                                     const float* __restrict__ y,
                                                     unsigned* __restrict__ ox,
                                                     unsigned* __restrict__ oy) {
    const float* in  = blockIdx.y ? y : x;
    unsigned*    out = blockIdx.y ? oy : ox;
    int row = blockIdx.x * 4 + (threadIdx.x >> 6);
    int t   = threadIdx.x & 63;
    float2 v = reinterpret_cast<const float2*>(in + (size_t)row * DF)[t];
    float s = v.x * v.x + v.y * v.y;
    #pragma unroll
    for (int o = 32; o; o >>= 1) s += __shfl_xor(s, o);
    float scale = 1.0f / fmaxf(sqrtf(s), 1e-12f);
    out[(size_t)row * 64 + t] = f2bf(v.x * scale) | (f2bf(v.y * scale) << 16);
}

// ---------------------------------------------- bf16 MFMA GEMM -> skew
// 128x128 tile, 256 thr (4 waves), K=128 staged once: A_lds/B_lds [128][136]
// bf16 (16B row pad -> conflict-free ds_read_b128 fragments). Wave w owns
// cols [32w,32w+32): acc[8 rt][2 ct] f32x4, 64 MFMAs. Inputs pre-normalized
// -> cost = (1 - dot)/ln2 directly. Epilogue reuses LDS as cs[128][130] and
// scatters anti-diagonals (R14 pattern, stride-129 reads conflict-free).
#define LDSTRIDE 272                         // bytes per LDS row (136 bf16)

__global__ __launch_bounds__(256) void sdtw_gemm_skew(const unsigned* __restrict__ xnb,
                                                      const unsigned* __restrict__ ynb,
                                                      float* __restrict__ skew) {
    __shared__ short smem[34816];            // 69,632 B: A 34,816 + B 34,816
    char* As = (char*)smem;
    char* Bs = (char*)smem + 34816;

    const int b  = blockIdx.z;
    const int r0 = blockIdx.y * 128;
    const int c0 = blockIdx.x * 128;
    const int tid = threadIdx.x;
    const int wid = tid >> 6, l = tid & 63;
    const int lr = l & 15, lg = l >> 4;

    const char* xg = (const char*)(xnb + ((size_t)b * TLEN + r0) * 64);
    const char* yg = (const char*)(ynb + ((size_t)b * TLEN + c0) * 64);

    // stage A and B tiles (each: 128 rows x 256 B global -> 272 B LDS rows)
    #pragma unroll
    for (int p = 0; p < 8; ++p) {
        int idx = p * 256 + tid;
        int row = idx >> 4, u = idx & 15;
        *(uint4*)(As + row * LDSTRIDE + u * 16) = *(const uint4*)(xg + row * 256 + u * 16);
        *(uint4*)(Bs + row * LDSTRIDE + u * 16) = *(const uint4*)(yg + row * 256 + u * 16);
    }
    __syncthreads();

    f32x4 acc[8][2];
    #pragma unroll
    for (int rt = 0; rt < 8; ++rt)
        #pragma unroll
        for (int ct = 0; ct < 2; ++ct) acc[rt][ct] = (f32x4){0.f, 0.f, 0.f, 0.f};

    #pragma unroll
    for (int kb = 0; kb < 4; ++kb) {         // K chunks of 32
        bf16x8 af[8], bf[2];
        #pragma unroll
        for (int rt = 0; rt < 8; ++rt)
            af[rt] = *(const bf16x8*)(As + (rt * 16 + lr) * LDSTRIDE + kb * 64 + lg * 16);
        #pragma unroll
        for (int ct = 0; ct < 2; ++ct)
            bf[ct] = *(const bf16x8*)(Bs + (wid * 32 + ct * 16 + lr) * LDSTRIDE + kb * 64 + lg * 16);
        #pragma unroll
        for (int rt = 0; rt < 8; ++rt)
            #pragma unroll
            for (int ct = 0; ct < 2; ++ct)
                acc[rt][ct] = __builtin_amdgcn_mfma_f32_16x16x32_bf16(af[rt], bf[ct], acc[rt][ct], 0, 0, 0);
    }

    __syncthreads();                         // all frag reads done; reuse LDS
    float* cs = (float*)smem;                // [128][130]
    #pragma unroll
    for (int rt = 0; rt < 8; ++rt)
        #pragma unroll
        for (int ct = 0; ct < 2; ++ct)
            #pragma unroll
            for (int r = 0; r < 4; ++r) {
                int row = rt * 16 + lg * 4 + r;          // C/D: row=(l>>4)*4+reg
                int col = wid * 32 + ct * 16 + lr;       //      col=l&15
                cs[row * 130 + col] = (1.0f - acc[rt][ct][r]) * INV_LN2;
            }
    __syncthreads();

    // anti-diagonal scatter: skew[kd*512 + r], contiguous in r
    float* sk = skew + (size_t)b * (NDIAG * TLEN);
    for (int dd = wid; dd < 255; dd += 4) {
        int lo = max(0, dd - 127), hi = min(127, dd);
        for (int rb = lo; rb <= hi; rb += 64) {
            int rl = rb + l;
            if (rl <= hi)
                sk[(size_t)(r0 + c0 + dd) * TLEN + r0 + rl] = cs[rl * 129 + dd]; // rl*130+(dd-rl)
        }
    }
}

// ----------------------------------------------------------------- DTW DP
// (R9/R14/R15 kernel, measured best ~91 us — unchanged.)
__device__ __forceinline__ int clampi(int v) {
    return v < 0 ? 0 : (v > NDIAG - 1 ? NDIAG - 1 : v);
}

__device__ __forceinline__ float dpp_shr1_old(float old, float x) {
    return __builtin_bit_cast(float,
        __builtin_amdgcn_update_dpp(__builtin_bit_cast(int, old),
                                    __builtin_bit_cast(int, x),
                                    0x138 /*wave_shr:1*/, 0xF, 0xF, false));
}

#define PH(s, CC, PN, PO, NQC, MASKED, CLAMPED)                                \
  {                                                                            \
    float up_ = dpp_shr1_old(bd_up, PN);     /* lane0 <- bd_up */              \
    float dg_ = dgs;                         /* patched up_ of prev phase */   \
    float m_   = fminf(fminf(dg_, PN), up_);                                   \
    float mid_ = __builtin_amdgcn_fmed3f(dg_, PN, up_);                        \
    float mx_  = fmaxf(fmaxf(dg_, PN), up_);                                   \
    float e_   = 1.0f + __builtin_amdgcn_exp2f(m_ - mid_)                      \
                      + __builtin_amdgcn_exp2f(m_ - mx_);                      \
    float v_   = CC + m_ - __builtin_amdgcn_logf(e_);                          \
    PO = (MASKED) ? (((unsigned)(vb0 + (s)) < 512u) ? v_ : vBig) : v_;         \
    if (((s) & 3) == 0) bq.x = PO;                                             \
    if (((s) & 3) == 1) bq.y = PO;                                             \
    if (((s) & 3) == 2) bq.z = PO;                                             \
    if (((s) & 3) == 3) { bq.w = PO;                                           \
      if (lt == 63) bnd4[c + 1][(q0 + ((s) >> 2)) & 7] = bq; }                 \
    bd_up = (NQC);                                                             \
    dgs = up_;                                                                 \
    { int kl_ = kd0 + (s) + 8; if (CLAMPED) kl_ = clampi(kl_);                 \
      CC = skb[(size_t)kl_ * TLEN]; }                                          \
  }

#define SEG_BODY(MASKED, CLAMPED)                                              \
    PH(0,  c0, P, Q, nq0.x, MASKED, CLAMPED) PH(1,  c1, Q, P, nq0.y, MASKED, CLAMPED) \
    PH(2,  c2, P, Q, nq0.z, MASKED, CLAMPED) PH(3,  c3, Q, P, nq0.w, MASKED, CLAMPED) \
    PH(4,  c4, P, Q, nq1.x, MASKED, CLAMPED) PH(5,  c5, Q, P, nq1.y, MASKED, CLAMPED) \
    PH(6,  c6, P, Q, nq1.z, MASKED, CLAMPED) PH(7,  c7, Q, P, nq1.w, MASKED, CLAMPED) \
    PH(8,  c0, P, Q, nq2.x, MASKED, CLAMPED) PH(9,  c1, Q, P, nq2.y, MASKED, CLAMPED) \
    PH(10, c2, P, Q, nq2.z, MASKED, CLAMPED) PH(11, c3, Q, P, nq2.w, MASKED, CLAMPED) \
    PH(12, c4, P, Q, nq3.x, MASKED, CLAMPED) PH(13, c5, Q, P, nq3.y, MASKED, CLAMPED) \
    PH(14, c6, P, Q, nq3.z, MASKED, CLAMPED) PH(15, c7, Q, P, nq3.w, MASKED, CLAMPED)

#define PRIME(K)                                                               \
    c0 = skb[(size_t)clampi((K) + 0) * TLEN];                                  \
    c1 = skb[(size_t)clampi((K) + 1) * TLEN];                                  \
    c2 = skb[(size_t)clampi((K) + 2) * TLEN];                                  \
    c3 = skb[(size_t)clampi((K) + 3) * TLEN];                                  \
    c4 = skb[(size_t)clampi((K) + 4) * TLEN];                                  \
    c5 = skb[(size_t)clampi((K) + 5) * TLEN];                                  \
    c6 = skb[(size_t)clampi((K) + 6) * TLEN];                                  \
    c7 = skb[(size_t)clampi((K) + 7) * TLEN];

__global__ __launch_bounds__(512) void sdtw_dp(const float* __restrict__ skew,
                                               float* __restrict__ out) {
    const int b   = blockIdx.x;
    const int tid = threadIdx.x;
    const int ww  = tid >> 6;
    const int c   = ((ww & 3) << 1) | (ww >> 2);
    const int lt  = tid & 63;
    const int row = 64 * c + lt;
    const float* skb = skew + (size_t)b * (NDIAG * TLEN) + row;

    __shared__ float4 bnd4[9][8];
    if (tid < 288) ((float*)bnd4)[tid] = BIGV;

    float P = BIGV, Q = BIGV;
    float vBig  = BIGV;
    float bd_up = BIGV;
    float dgs   = (tid == 0) ? 0.0f : BIGV;
    float4 bq = make_float4(BIGV, BIGV, BIGV, BIGV);

    __syncthreads();

    float c0, c1, c2, c3, c4, c5, c6, c7;
    PRIME(-16 * c)

    for (int s = 0; s < 71; ++s) {
        const int sw  = s - 5 * c;
        const int kd0 = 16 * (s - c);
        const int q0  = (kd0 >> 2) & 7;
        const int vb0 = kd0 - row;

        if (sw >= -1 && sw <= 35) {
            float4 nq0 = bnd4[c][q0];
            float4 nq1 = bnd4[c][(q0 + 1) & 7];
            float4 nq2 = bnd4[c][(q0 + 2) & 7];
            float4 nq3 = bnd4[c][(q0 + 3) & 7];
            if (sw == -1) { PRIME(kd0) }
            if (sw >= 4 && sw <= 31) { SEG_BODY(0, 0) }
            else                     { SEG_BODY(1, 1) }
        } else {
            if (lt == 63) {
                float4 bigq = make_float4(BIGV, BIGV, BIGV, BIGV);
                bnd4[c + 1][q0]           = bigq;
                bnd4[c + 1][(q0 + 1) & 7] = bigq;
                bnd4[c + 1][(q0 + 2) & 7] = bigq;
                bnd4[c + 1][(q0 + 3) & 7] = bigq;
            }
        }
        __syncthreads();
    }

    if (tid == 511) out[b] = Q * LN2;
}

// ---------------------------------------------------------------- launcher
extern "C" void kernel_launch(void* const* d_in, const int* in_sizes, int n_in,
                              void* d_out, int out_size, void* d_ws, size_t ws_size,
                              hipStream_t stream) {
    const float* x = (const float*)d_in[0];
    const float* y = (const float*)d_in[1];
    float* outp = (float*)d_out;

    float*    skew = (float*)d_ws;                        // 16,760,832 floats
    unsigned* xnb  = (unsigned*)(skew + (size_t)16760832);
    unsigned* ynb  = xnb + 1048576;

    sdtw_normcast<<<dim3(BT * TLEN / 4, 2), dim3(256), 0, stream>>>(x, y, xnb, ynb);
    sdtw_gemm_skew<<<dim3(4, 4, BT), dim3(256), 0, stream>>>(xnb, ynb, skew);
    sdtw_dp<<<dim3(BT), dim3(512), 0, stream>>>(skew, outp);
}